// Round 7
// baseline (315.159 us; speedup 1.0000x reference)
//
#include <hip/hip_runtime.h>

using u16 = unsigned short;
typedef __attribute__((ext_vector_type(8))) __bf16 bf16x8;
typedef __attribute__((ext_vector_type(4))) float f32x4;
typedef __attribute__((ext_vector_type(8))) u16 u16x8;
typedef __attribute__((ext_vector_type(4))) u16 u16x4;
typedef __attribute__((ext_vector_type(4))) float floatx4;

__device__ __forceinline__ u16 f2b(float f) {
    __bf16 h = (__bf16)f;
    return __builtin_bit_cast(u16, h);
}

__device__ __forceinline__ void gload16(const void* g, void* l) {
    __builtin_amdgcn_global_load_lds((const __attribute__((address_space(1))) void*)g,
                                     (__attribute__((address_space(3))) void*)l, 16, 0, 0);
}

constexpr int Hdim = 1024, Bdim = 2, Sdim = 2048, Dh = 64;
constexpr int NTOK = Bdim * Sdim; // 4096

// ---------------- cast x -> bf16 (vectorized) ----------------
__global__ void cast_x_kernel(const float* __restrict__ x, u16* __restrict__ xb, int n4) {
    int i = blockIdx.x * blockDim.x + threadIdx.x;
    int stride = gridDim.x * blockDim.x;
    for (; i < n4; i += stride) {
        floatx4 v = reinterpret_cast<const floatx4*>(x)[i];
        u16x4 o;
        #pragma unroll
        for (int j = 0; j < 4; ++j) o[j] = f2b(v[j]);
        reinterpret_cast<u16x4*>(xb)[i] = o;
    }
}

// ---------------- cast + transpose 4 weights: T[n][k] = W[k][n] ----------------
__global__ void transpose_cast_w(const float* __restrict__ W0, const float* __restrict__ W1,
                                 const float* __restrict__ W2, const float* __restrict__ W3,
                                 u16* __restrict__ T0, u16* __restrict__ T1,
                                 u16* __restrict__ T2, u16* __restrict__ T3) {
    __shared__ float tile[32][33];
    const float* W; u16* T;
    switch (blockIdx.z) {
        case 0: W = W0; T = T0; break;
        case 1: W = W1; T = T1; break;
        case 2: W = W2; T = T2; break;
        default: W = W3; T = T3; break;
    }
    int bx = blockIdx.x * 32, by = blockIdx.y * 32;
    int tx = threadIdx.x, ty = threadIdx.y;
    #pragma unroll
    for (int i = 0; i < 4; ++i)
        tile[ty + i * 8][tx] = W[(size_t)(by + ty + i * 8) * Hdim + bx + tx];
    __syncthreads();
    #pragma unroll
    for (int i = 0; i < 4; ++i)
        T[(size_t)(bx + ty + i * 8) * Hdim + by + tx] = f2b(tile[tx][ty + i * 8]);
}

// ---------------- bf16 GEMM: C = A[M][K] * Bt[N][K]^T ----------------
// 128xBN tile, BK=64 (2 MFMA k-steps per stage; halves barrier count),
// 4 waves (2x2); wave covers 64 rows x BN/2 cols (NB = BN/32 frags).
// global_load_lds(16B), linear LDS.
// MODE 0: bf16 C; MODE 1: f32 C; MODE 2: QKV split (Q, K token-major; V^T).
template <int MODE, int BN>
__global__ __launch_bounds__(256) void gemm_bt(const u16* __restrict__ A, const u16* __restrict__ Bt,
                                               void* __restrict__ C0, void* __restrict__ C1,
                                               void* __restrict__ C2, int N, int K) {
    constexpr int NB = BN / 32;
    __shared__ __align__(16) u16 As[128 * 64];
    __shared__ __align__(16) u16 Bs[BN * 64];
    const int tid = threadIdx.x;
    const int lane = tid & 63, wid = tid >> 6;
    const int wr = wid >> 1, wc = wid & 1;
    const int fr = lane & 15, g = lane >> 4;
    const int rowBase = blockIdx.y * 128, colBase = blockIdx.x * BN;
    const int sr = lane >> 3, sc = (lane & 7) * 8;   // 8 rows x 128B per wave-issue
    f32x4 acc[4][NB] = {};
    for (int k0 = 0; k0 < K; k0 += 64) {
        __syncthreads();
        #pragma unroll
        for (int i = 0; i < 4; ++i) {
            const int rb = i * 32 + wid * 8;
            gload16(&A[(size_t)(rowBase + rb + sr) * K + k0 + sc], &As[rb * 64]);
        }
        #pragma unroll
        for (int i = 0; i < BN / 32; ++i) {
            const int rb = i * 32 + wid * 8;
            gload16(&Bt[(size_t)(colBase + rb + sr) * K + k0 + sc], &Bs[rb * 64]);
        }
        __syncthreads();
        #pragma unroll
        for (int kk = 0; kk < 2; ++kk) {
            bf16x8 af[4], bfr[NB];
            #pragma unroll
            for (int m = 0; m < 4; ++m)
                af[m] = *reinterpret_cast<const bf16x8*>(&As[(wr * 64 + m * 16 + fr) * 64 + kk * 32 + g * 8]);
            #pragma unroll
            for (int n = 0; n < NB; ++n)
                bfr[n] = *reinterpret_cast<const bf16x8*>(&Bs[(wc * (BN / 2) + n * 16 + fr) * 64 + kk * 32 + g * 8]);
            #pragma unroll
            for (int m = 0; m < 4; ++m)
                #pragma unroll
                for (int n = 0; n < NB; ++n)
                    acc[m][n] = __builtin_amdgcn_mfma_f32_16x16x32_bf16(af[m], bfr[n], acc[m][n], 0, 0, 0);
        }
    }
    #pragma unroll
    for (int m = 0; m < 4; ++m) {
        #pragma unroll
        for (int n = 0; n < NB; ++n) {
            const int row = rowBase + wr * 64 + m * 16 + g * 4;
            const int col = colBase + wc * (BN / 2) + n * 16 + fr;
            if constexpr (MODE == 0) {
                u16* C = (u16*)C0;
                #pragma unroll
                for (int j = 0; j < 4; ++j) C[(size_t)(row + j) * N + col] = f2b(acc[m][n][j]);
            } else if constexpr (MODE == 1) {
                float* C = (float*)C0;
                #pragma unroll
                for (int j = 0; j < 4; ++j) C[(size_t)(row + j) * N + col] = acc[m][n][j];
            } else {
                if (col < 1024) {
                    u16* Qm = (u16*)C0;
                    #pragma unroll
                    for (int j = 0; j < 4; ++j) Qm[(size_t)(row + j) * 1024 + col] = f2b(acc[m][n][j]);
                } else if (col < 2048) {
                    u16* Km = (u16*)C1;
                    #pragma unroll
                    for (int j = 0; j < 4; ++j) Km[(size_t)(row + j) * 1024 + (col - 1024)] = f2b(acc[m][n][j]);
                } else {
                    u16* Vt = (u16*)C2;
                    u16x4 pk;
                    #pragma unroll
                    for (int j = 0; j < 4; ++j) pk[j] = f2b(acc[m][n][j]);
                    *reinterpret_cast<u16x4*>(&Vt[(size_t)(col - 2048) * NTOK + row]) = pk;
                }
            }
        }
    }
}

// ---------------- causal flash attention ----------------
// 1024 blocks, 64 q-rows each, heavy-first (qb descending in dispatch order),
// XCD-grouped (bid%8 selects (h,b)%8 so a group's K/V stays in one XCD L2).
// 4 waves; wave w owns q rows [qb*64 + w*16, +16). KV tiles 64, double-buffered
// via global_load_lds with pre-swizzled src (byte ^= (row&7)<<4): 2-way reads.
// 41KB LDS -> 3 blocks/CU (12 waves/CU).
__global__ __launch_bounds__(256, 3) void attn_kernel(const u16* __restrict__ Q, const u16* __restrict__ Km,
                                                      const u16* __restrict__ VtG, u16* __restrict__ AO) {
    __shared__ __align__(16) u16 Kt[2][64 * 64];
    __shared__ __align__(16) u16 Vt[2][64 * 64];
    __shared__ __align__(16) u16 Pw[4][16][72];
    const int tid = threadIdx.x, lane = tid & 63, w = tid >> 6;
    const int bid = blockIdx.x;
    const int xg = bid & 7, rem = bid >> 3;
    const int qi = rem & 31, yg = rem >> 5;
    const int grp = xg + 8 * yg;          // (h,b) group 0..31
    const int h = grp & 15, b = grp >> 4;
    const int qb = 31 - qi;               // heavy blocks dispatch first
    const int h0 = h * Dh;
    const size_t boff = (size_t)b * Sdim * Hdim;
    const u16* Qb = Q + boff;
    u16* AOb = AO + boff;
    const int fr = lane & 15, g = lane >> 4;
    const int qrow0 = qb * 64 + w * 16;

    // staging lane geometry (pre-swizzled source cols)
    const int lr = lane >> 3;
    const int lc8 = ((lane & 7) ^ lr) * 8;
    const u16* Kg = Km + boff + (size_t)(w * 8 + lr) * Hdim + h0 + lc8;
    const u16* Vg = VtG + (size_t)(h0 + w * 8 + lr) * NTOK + (size_t)b * Sdim + lc8;

    auto stage = [&](int t, int bufi) {
        const int kv0 = t * 64;
        #pragma unroll
        for (int i = 0; i < 2; ++i) {
            gload16(Kg + (size_t)(kv0 + i * 32) * Hdim, &Kt[bufi][w * 512 + i * 2048]);
            gload16(Vg + (size_t)(i * 32) * NTOK + kv0, &Vt[bufi][w * 512 + i * 2048]);
        }
    };

    // Q fragments (16 rows x 64 d), prescaled by 1/8 * log2(e) (exp -> exp2)
    constexpr float QSCALE = 0.125f * 1.44269504089f;
    bf16x8 qf[2];
    #pragma unroll
    for (int c = 0; c < 2; ++c) {
        bf16x8 t = *reinterpret_cast<const bf16x8*>(
            &Qb[(size_t)(qrow0 + fr) * Hdim + h0 + c * 32 + g * 8]);
        bf16x8 r;
        #pragma unroll
        for (int j = 0; j < 8; ++j) r[j] = (__bf16)((float)t[j] * QSCALE);
        qf[c] = r;
    }

    f32x4 o[4] = {};
    float mrow[4], lrow[4];
    #pragma unroll
    for (int j = 0; j < 4; ++j) { mrow[j] = -INFINITY; lrow[j] = 0.f; }

    const int ntiles = qb + 1;
    stage(0, 0);
    __syncthreads();
    int buf = 0;
    for (int t = 0; t < ntiles; ++t) {
        if (t + 1 < ntiles) stage(t + 1, buf ^ 1);
        const int kv0 = t * 64;
        const bool masked = (t == qb);
        // ---- QK^T ----
        f32x4 s[4];
        __builtin_amdgcn_s_setprio(1);
        #pragma unroll
        for (int n = 0; n < 4; ++n) {
            const int row = n * 16 + fr;
            const int sw = (row & 7) << 3;
            const u16* kp = &Kt[buf][row * 64];
            bf16x8 kf0 = *reinterpret_cast<const bf16x8*>(&kp[(g * 8) ^ sw]);
            bf16x8 kf1 = *reinterpret_cast<const bf16x8*>(&kp[(32 + g * 8) ^ sw]);
            f32x4 z = {};
            z = __builtin_amdgcn_mfma_f32_16x16x32_bf16(qf[0], kf0, z, 0, 0, 0);
            s[n] = __builtin_amdgcn_mfma_f32_16x16x32_bf16(qf[1], kf1, z, 0, 0, 0);
        }
        __builtin_amdgcn_s_setprio(0);
        // ---- online softmax (base-2 domain, defer-max THR=8) ----
        #pragma unroll
        for (int j = 0; j < 4; ++j) {
            const int qrow = qrow0 + g * 4 + j;
            float mx = -3.0e38f;
            #pragma unroll
            for (int n = 0; n < 4; ++n) {
                float v = s[n][j];
                if (masked) {
                    int kv = kv0 + n * 16 + fr;
                    v = (kv <= qrow) ? v : -3.0e38f;
                    s[n][j] = v;
                }
                mx = fmaxf(mx, v);
            }
            #pragma unroll
            for (int off = 1; off < 16; off <<= 1) mx = fmaxf(mx, __shfl_xor(mx, off));
            const bool skip = (__all(mx <= mrow[j] + 8.0f) != 0);   // wave-uniform
            const float mnew = skip ? mrow[j] : fmaxf(mrow[j], mx);
            float rs = 0.f;
            #pragma unroll
            for (int n = 0; n < 4; ++n) {
                float pv = exp2f(s[n][j] - mnew);
                rs += pv;
                Pw[w][g * 4 + j][n * 16 + fr] = f2b(pv);
            }
            #pragma unroll
            for (int off = 1; off < 16; off <<= 1) rs += __shfl_xor(rs, off);
            if (skip) {
                lrow[j] += rs;
            } else {
                const float alpha = exp2f(mrow[j] - mnew);
                lrow[j] = lrow[j] * alpha + rs;
                mrow[j] = mnew;
                #pragma unroll
                for (int n = 0; n < 4; ++n) o[n][j] *= alpha;
            }
        }
        // ---- PV ----
        bf16x8 pa0 = *reinterpret_cast<const bf16x8*>(&Pw[w][fr][g * 8]);
        bf16x8 pa1 = *reinterpret_cast<const bf16x8*>(&Pw[w][fr][32 + g * 8]);
        __builtin_amdgcn_s_setprio(1);
        #pragma unroll
        for (int n = 0; n < 4; ++n) {
            const int row = n * 16 + fr;
            const int sw = (row & 7) << 3;
            const u16* vp = &Vt[buf][row * 64];
            bf16x8 vf0 = *reinterpret_cast<const bf16x8*>(&vp[(g * 8) ^ sw]);
            bf16x8 vf1 = *reinterpret_cast<const bf16x8*>(&vp[(32 + g * 8) ^ sw]);
            o[n] = __builtin_amdgcn_mfma_f32_16x16x32_bf16(pa0, vf0, o[n], 0, 0, 0);
            o[n] = __builtin_amdgcn_mfma_f32_16x16x32_bf16(pa1, vf1, o[n], 0, 0, 0);
        }
        __builtin_amdgcn_s_setprio(0);
        __syncthreads();
        buf ^= 1;
    }

    float invl[4];
    #pragma unroll
    for (int j = 0; j < 4; ++j) invl[j] = 1.0f / lrow[j];
    #pragma unroll
    for (int n = 0; n < 4; ++n)
        #pragma unroll
        for (int j = 0; j < 4; ++j) {
            int qrow = qrow0 + g * 4 + j;
            AOb[(size_t)qrow * Hdim + h0 + n * 16 + fr] = f2b(o[n][j] * invl[j]);
        }
}

extern "C" void kernel_launch(void* const* d_in, const int* in_sizes, int n_in,
                              void* d_out, int out_size, void* d_ws, size_t ws_size,
                              hipStream_t stream) {
    const float* x  = (const float*)d_in[0];
    // d_in[1] = causal mask — applied analytically
    const float* Wq = (const float*)d_in[2];
    const float* Wk = (const float*)d_in[3];
    const float* Wv = (const float*)d_in[4];
    const float* Wo = (const float*)d_in[5];
    float* out = (float*)d_out;

    u16* ws  = (u16*)d_ws;
    u16* Xb  = ws;                    // 4096x1024
    u16* WqT = ws  + 4194304;         // 3x 1024x1024 contiguous => fused QKV B
    u16* WkT = WqT + 1048576;
    u16* WvT = WkT + 1048576;
    u16* WoT = WvT + 1048576;
    u16* Qm  = WoT + 1048576;         // 4096x1024 token-major
    u16* Km  = Qm  + 4194304;
    u16* Vt  = Km  + 4194304;         // V^T: [1024 hd][4096 token]
    u16* AO  = Vt  + 4194304;

    cast_x_kernel<<<2048, 256, 0, stream>>>(x, Xb, NTOK * Hdim / 4);
    transpose_cast_w<<<dim3(32, 32, 4), dim3(32, 8), 0, stream>>>(Wq, Wk, Wv, Wo, WqT, WkT, WvT, WoT);
    gemm_bt<2, 128><<<dim3(24, 32), 256, 0, stream>>>(Xb, WqT, Qm, Km, Vt, 3072, Hdim);
    attn_kernel<<<dim3(1024), 256, 0, stream>>>(Qm, Km, Vt, AO);
    gemm_bt<1, 64><<<dim3(16, 32), 256, 0, stream>>>(AO, WoT, out, nullptr, nullptr, Hdim, Hdim);
}

// Round 8
// 238.212 us; speedup vs baseline: 1.3230x; 1.3230x over previous
//
#include <hip/hip_runtime.h>

using u16 = unsigned short;
typedef __attribute__((ext_vector_type(8))) __bf16 bf16x8;
typedef __attribute__((ext_vector_type(4))) float f32x4;
typedef __attribute__((ext_vector_type(8))) u16 u16x8;
typedef __attribute__((ext_vector_type(4))) u16 u16x4;
typedef __attribute__((ext_vector_type(4))) float floatx4;

__device__ __forceinline__ u16 f2b(float f) {
    __bf16 h = (__bf16)f;
    return __builtin_bit_cast(u16, h);
}

__device__ __forceinline__ void gload16(const void* g, void* l) {
    __builtin_amdgcn_global_load_lds((const __attribute__((address_space(1))) void*)g,
                                     (__attribute__((address_space(3))) void*)l, 16, 0, 0);
}

constexpr int Hdim = 1024, Bdim = 2, Sdim = 2048, Dh = 64;
constexpr int NTOK = Bdim * Sdim; // 4096

// ---------------- cast x -> bf16 (vectorized) ----------------
__global__ void cast_x_kernel(const float* __restrict__ x, u16* __restrict__ xb, int n4) {
    int i = blockIdx.x * blockDim.x + threadIdx.x;
    int stride = gridDim.x * blockDim.x;
    for (; i < n4; i += stride) {
        floatx4 v = reinterpret_cast<const floatx4*>(x)[i];
        u16x4 o;
        #pragma unroll
        for (int j = 0; j < 4; ++j) o[j] = f2b(v[j]);
        reinterpret_cast<u16x4*>(xb)[i] = o;
    }
}

// ---------------- cast + transpose 4 weights: T[n][k] = W[k][n] ----------------
__global__ void transpose_cast_w(const float* __restrict__ W0, const float* __restrict__ W1,
                                 const float* __restrict__ W2, const float* __restrict__ W3,
                                 u16* __restrict__ T0, u16* __restrict__ T1,
                                 u16* __restrict__ T2, u16* __restrict__ T3) {
    __shared__ float tile[32][33];
    const float* W; u16* T;
    switch (blockIdx.z) {
        case 0: W = W0; T = T0; break;
        case 1: W = W1; T = T1; break;
        case 2: W = W2; T = T2; break;
        default: W = W3; T = T3; break;
    }
    int bx = blockIdx.x * 32, by = blockIdx.y * 32;
    int tx = threadIdx.x, ty = threadIdx.y;
    #pragma unroll
    for (int i = 0; i < 4; ++i)
        tile[ty + i * 8][tx] = W[(size_t)(by + ty + i * 8) * Hdim + bx + tx];
    __syncthreads();
    #pragma unroll
    for (int i = 0; i < 4; ++i)
        T[(size_t)(bx + ty + i * 8) * Hdim + by + tx] = f2b(tile[tx][ty + i * 8]);
}

// ---------------- bf16 GEMM: C = A[M][K] * Bt[N][K]^T ---------------- (R6 BK=32)
template <int MODE, int BN>
__global__ __launch_bounds__(256) void gemm_bt(const u16* __restrict__ A, const u16* __restrict__ Bt,
                                               void* __restrict__ C0, void* __restrict__ C1,
                                               void* __restrict__ C2, int N, int K) {
    constexpr int NB = BN / 32;  // col-frags per wave (wave covers BN/2 cols)
    __shared__ __align__(16) u16 As[128 * 32];
    __shared__ __align__(16) u16 Bs[BN * 32];
    const int tid = threadIdx.x;
    const int lane = tid & 63, wid = tid >> 6;
    const int wr = wid >> 1, wc = wid & 1;
    const int fr = lane & 15, g = lane >> 4, k8 = g * 8;
    const int rowBase = blockIdx.y * 128, colBase = blockIdx.x * BN;
    const int sr = lane >> 2, sc = (lane & 3) * 8;
    f32x4 acc[4][NB] = {};
    for (int k0 = 0; k0 < K; k0 += 32) {
        __syncthreads();
        #pragma unroll
        for (int i = 0; i < 2; ++i) {
            const int rb = wid * 32 + i * 16;
            gload16(&A[(size_t)(rowBase + rb + sr) * K + k0 + sc], &As[rb * 32]);
        }
        if constexpr (BN == 128) {
            #pragma unroll
            for (int i = 0; i < 2; ++i) {
                const int rb = wid * 32 + i * 16;
                gload16(&Bt[(size_t)(colBase + rb + sr) * K + k0 + sc], &Bs[rb * 32]);
            }
        } else {
            const int rb = wid * 16;
            gload16(&Bt[(size_t)(colBase + rb + sr) * K + k0 + sc], &Bs[rb * 32]);
        }
        __syncthreads();
        bf16x8 af[4], bfr[NB];
        #pragma unroll
        for (int m = 0; m < 4; ++m)
            af[m] = *reinterpret_cast<const bf16x8*>(&As[(wr * 64 + m * 16 + fr) * 32 + k8]);
        #pragma unroll
        for (int n = 0; n < NB; ++n)
            bfr[n] = *reinterpret_cast<const bf16x8*>(&Bs[(wc * (BN / 2) + n * 16 + fr) * 32 + k8]);
        #pragma unroll
        for (int m = 0; m < 4; ++m)
            #pragma unroll
            for (int n = 0; n < NB; ++n)
                acc[m][n] = __builtin_amdgcn_mfma_f32_16x16x32_bf16(af[m], bfr[n], acc[m][n], 0, 0, 0);
    }
    #pragma unroll
    for (int m = 0; m < 4; ++m) {
        #pragma unroll
        for (int n = 0; n < NB; ++n) {
            const int row = rowBase + wr * 64 + m * 16 + g * 4;
            const int col = colBase + wc * (BN / 2) + n * 16 + fr;
            if constexpr (MODE == 0) {
                u16* C = (u16*)C0;
                #pragma unroll
                for (int j = 0; j < 4; ++j) C[(size_t)(row + j) * N + col] = f2b(acc[m][n][j]);
            } else if constexpr (MODE == 1) {
                float* C = (float*)C0;
                #pragma unroll
                for (int j = 0; j < 4; ++j) C[(size_t)(row + j) * N + col] = acc[m][n][j];
            } else {
                if (col < 1024) {
                    u16* Qm = (u16*)C0;
                    #pragma unroll
                    for (int j = 0; j < 4; ++j) Qm[(size_t)(row + j) * 1024 + col] = f2b(acc[m][n][j]);
                } else if (col < 2048) {
                    u16* Km = (u16*)C1;
                    #pragma unroll
                    for (int j = 0; j < 4; ++j) Km[(size_t)(row + j) * 1024 + (col - 1024)] = f2b(acc[m][n][j]);
                } else {
                    u16* Vt = (u16*)C2;
                    u16x4 pk;
                    #pragma unroll
                    for (int j = 0; j < 4; ++j) pk[j] = f2b(acc[m][n][j]);
                    *reinterpret_cast<u16x4*>(&Vt[(size_t)(col - 2048) * NTOK + row]) = pk;
                }
            }
        }
    }
}

// ---------------- causal flash attention, pair-balanced (R6 structure) --------
// 512 uniform blocks; block handles q-blocks {p, 31-p} (64 rows each) of one
// (h,b). Every block: exactly 33 tile-computes. XCD-grouped via bid%8.
// Wave w owns rows [w*16,+16) of each q-block. K/V LDS double-buffered,
// XOR-swizzle via pre-swizzled global source. + native bf16 cast + defer-max.
__global__ __launch_bounds__(256, 2) void attn_kernel(const u16* __restrict__ Q, const u16* __restrict__ Km,
                                                      const u16* __restrict__ VtG, u16* __restrict__ AO) {
    __shared__ __align__(16) u16 Kt[2][64 * 64];
    __shared__ __align__(16) u16 Vt[2][64 * 64];
    __shared__ __align__(16) u16 Pw[4][32][72];
    const int tid = threadIdx.x, lane = tid & 63, w = tid >> 6;
    const int bid = blockIdx.x;
    const int xg = bid & 7, rem = bid >> 3;
    const int p = rem & 15, yg = rem >> 4;
    const int grp = xg + 8 * yg;          // (h,b) group 0..31
    const int h = grp & 15, b = grp >> 4;
    const int qsel[2] = { p, 31 - p };
    const int h0 = h * Dh;
    const size_t boff = (size_t)b * Sdim * Hdim;
    const u16* Qb = Q + boff;
    u16* AOb = AO + boff;
    const int fr = lane & 15, g = lane >> 4;

    // staging lane geometry (pre-swizzled source cols)
    const int lr = lane >> 3;
    const int lc8 = ((lane & 7) ^ lr) * 8;
    const u16* Kg = Km + boff + (size_t)(w * 8 + lr) * Hdim + h0 + lc8;
    const u16* Vg = VtG + (size_t)(h0 + w * 8 + lr) * NTOK + (size_t)b * Sdim + lc8;

    auto stage = [&](int t, int bufi) {
        const int kv0 = t * 64;
        #pragma unroll
        for (int i = 0; i < 2; ++i) {
            gload16(Kg + (size_t)(kv0 + i * 32) * Hdim, &Kt[bufi][w * 512 + i * 2048]);
            gload16(Vg + (size_t)(i * 32) * NTOK + kv0, &Vt[bufi][w * 512 + i * 2048]);
        }
    };

    // Q fragments for both q-blocks, prescaled by 1/8 * log2(e) (exp -> exp2)
    constexpr float QSCALE = 0.125f * 1.44269504089f;
    bf16x8 qf[2][2];
    int qrow0[2];
    #pragma unroll
    for (int m = 0; m < 2; ++m) {
        qrow0[m] = qsel[m] * 64 + w * 16;
        #pragma unroll
        for (int c = 0; c < 2; ++c) {
            bf16x8 t = *reinterpret_cast<const bf16x8*>(
                &Qb[(size_t)(qrow0[m] + fr) * Hdim + h0 + c * 32 + g * 8]);
            bf16x8 r;
            #pragma unroll
            for (int j = 0; j < 8; ++j) r[j] = (__bf16)((float)t[j] * QSCALE);
            qf[m][c] = r;
        }
    }

    f32x4 o[2][4] = {};
    float mrow[2][4], lrow[2][4];
    #pragma unroll
    for (int m = 0; m < 2; ++m)
        #pragma unroll
        for (int j = 0; j < 4; ++j) { mrow[m][j] = -INFINITY; lrow[m][j] = 0.f; }

    const int ntiles = qsel[1] + 1;
    stage(0, 0);
    __syncthreads();
    int buf = 0;
    for (int t = 0; t < ntiles; ++t) {
        if (t + 1 < ntiles) stage(t + 1, buf ^ 1);
        const int kv0 = t * 64;
        #pragma unroll
        for (int m = 0; m < 2; ++m) {
            if (t > qsel[m]) continue;            // block-uniform
            const bool masked = (t == qsel[m]);
            // ---- QK^T ----
            f32x4 s[4];
            __builtin_amdgcn_s_setprio(1);
            #pragma unroll
            for (int n = 0; n < 4; ++n) {
                const int row = n * 16 + fr;
                const int sw = (row & 7) << 3;
                const u16* kp = &Kt[buf][row * 64];
                bf16x8 kf0 = *reinterpret_cast<const bf16x8*>(&kp[(g * 8) ^ sw]);
                bf16x8 kf1 = *reinterpret_cast<const bf16x8*>(&kp[(32 + g * 8) ^ sw]);
                f32x4 z = {};
                z = __builtin_amdgcn_mfma_f32_16x16x32_bf16(qf[m][0], kf0, z, 0, 0, 0);
                s[n] = __builtin_amdgcn_mfma_f32_16x16x32_bf16(qf[m][1], kf1, z, 0, 0, 0);
            }
            __builtin_amdgcn_s_setprio(0);
            // ---- online softmax (base-2 domain, defer-max THR=8) ----
            #pragma unroll
            for (int j = 0; j < 4; ++j) {
                const int qrow = qrow0[m] + g * 4 + j;
                float mx = -3.0e38f;
                #pragma unroll
                for (int n = 0; n < 4; ++n) {
                    float v = s[n][j];
                    if (masked) {
                        int kv = kv0 + n * 16 + fr;
                        v = (kv <= qrow) ? v : -3.0e38f;
                        s[n][j] = v;
                    }
                    mx = fmaxf(mx, v);
                }
                #pragma unroll
                for (int off = 1; off < 16; off <<= 1) mx = fmaxf(mx, __shfl_xor(mx, off));
                const bool skip = (__all(mx <= mrow[m][j] + 8.0f) != 0);   // wave-uniform
                const float mnew = skip ? mrow[m][j] : fmaxf(mrow[m][j], mx);
                float rs = 0.f;
                #pragma unroll
                for (int n = 0; n < 4; ++n) {
                    float pv = exp2f(s[n][j] - mnew);
                    rs += pv;
                    Pw[w][m * 16 + g * 4 + j][n * 16 + fr] = f2b(pv);
                }
                #pragma unroll
                for (int off = 1; off < 16; off <<= 1) rs += __shfl_xor(rs, off);
                if (skip) {
                    lrow[m][j] += rs;
                } else {
                    const float alpha = exp2f(mrow[m][j] - mnew);
                    lrow[m][j] = lrow[m][j] * alpha + rs;
                    mrow[m][j] = mnew;
                    #pragma unroll
                    for (int n = 0; n < 4; ++n) o[m][n][j] *= alpha;
                }
            }
            // ---- PV ----
            bf16x8 pa0 = *reinterpret_cast<const bf16x8*>(&Pw[w][m * 16 + fr][g * 8]);
            bf16x8 pa1 = *reinterpret_cast<const bf16x8*>(&Pw[w][m * 16 + fr][32 + g * 8]);
            __builtin_amdgcn_s_setprio(1);
            #pragma unroll
            for (int n = 0; n < 4; ++n) {
                const int row = n * 16 + fr;
                const int sw = (row & 7) << 3;
                const u16* vp = &Vt[buf][row * 64];
                bf16x8 vf0 = *reinterpret_cast<const bf16x8*>(&vp[(g * 8) ^ sw]);
                bf16x8 vf1 = *reinterpret_cast<const bf16x8*>(&vp[(32 + g * 8) ^ sw]);
                o[m][n] = __builtin_amdgcn_mfma_f32_16x16x32_bf16(pa0, vf0, o[m][n], 0, 0, 0);
                o[m][n] = __builtin_amdgcn_mfma_f32_16x16x32_bf16(pa1, vf1, o[m][n], 0, 0, 0);
            }
            __builtin_amdgcn_s_setprio(0);
        }
        __syncthreads();
        buf ^= 1;
    }

    #pragma unroll
    for (int m = 0; m < 2; ++m) {
        float invl[4];
        #pragma unroll
        for (int j = 0; j < 4; ++j) invl[j] = 1.0f / lrow[m][j];
        #pragma unroll
        for (int n = 0; n < 4; ++n)
            #pragma unroll
            for (int j = 0; j < 4; ++j) {
                int qrow = qrow0[m] + g * 4 + j;
                AOb[(size_t)qrow * Hdim + h0 + n * 16 + fr] = f2b(o[m][n][j] * invl[j]);
            }
    }
}

extern "C" void kernel_launch(void* const* d_in, const int* in_sizes, int n_in,
                              void* d_out, int out_size, void* d_ws, size_t ws_size,
                              hipStream_t stream) {
    const float* x  = (const float*)d_in[0];
    // d_in[1] = causal mask — applied analytically
    const float* Wq = (const float*)d_in[2];
    const float* Wk = (const float*)d_in[3];
    const float* Wv = (const float*)d_in[4];
    const float* Wo = (const float*)d_in[5];
    float* out = (float*)d_out;

    u16* ws  = (u16*)d_ws;
    u16* Xb  = ws;                    // 4096x1024
    u16* WqT = ws  + 4194304;         // 3x 1024x1024 contiguous => fused QKV B
    u16* WkT = WqT + 1048576;
    u16* WvT = WkT + 1048576;
    u16* WoT = WvT + 1048576;
    u16* Qm  = WoT + 1048576;         // 4096x1024 token-major
    u16* Km  = Qm  + 4194304;
    u16* Vt  = Km  + 4194304;         // V^T: [1024 hd][4096 token]
    u16* AO  = Vt  + 4194304;

    cast_x_kernel<<<2048, 256, 0, stream>>>(x, Xb, NTOK * Hdim / 4);
    transpose_cast_w<<<dim3(32, 32, 4), dim3(32, 8), 0, stream>>>(Wq, Wk, Wv, Wo, WqT, WkT, WvT, WoT);
    gemm_bt<2, 128><<<dim3(24, 32), 256, 0, stream>>>(Xb, WqT, Qm, Km, Vt, 3072, Hdim);
    attn_kernel<<<dim3(512), 256, 0, stream>>>(Qm, Km, Vt, AO);
    gemm_bt<1, 64><<<dim3(16, 32), 256, 0, stream>>>(AO, WoT, out, nullptr, nullptr, Hdim, Hdim);
}

// Round 12
// 208.036 us; speedup vs baseline: 1.5149x; 1.1450x over previous
//
#include <hip/hip_runtime.h>

using u16 = unsigned short;
typedef __attribute__((ext_vector_type(8))) __bf16 bf16x8;
typedef __attribute__((ext_vector_type(4))) float f32x4;
typedef __attribute__((ext_vector_type(8))) u16 u16x8;
typedef __attribute__((ext_vector_type(4))) u16 u16x4;
typedef __attribute__((ext_vector_type(4))) float floatx4;

__device__ __forceinline__ u16 f2b(float f) {
    __bf16 h = (__bf16)f;
    return __builtin_bit_cast(u16, h);
}

__device__ __forceinline__ void gload16(const void* g, void* l) {
    __builtin_amdgcn_global_load_lds((const __attribute__((address_space(1))) void*)g,
                                     (__attribute__((address_space(3))) void*)l, 16, 0, 0);
}

constexpr int Hdim = 1024, Bdim = 2, Sdim = 2048, Dh = 64;
constexpr int NTOK = Bdim * Sdim; // 4096

// ---------------- cast x -> bf16 (vectorized) ----------------
__global__ void cast_x_kernel(const float* __restrict__ x, u16* __restrict__ xb, int n4) {
    int i = blockIdx.x * blockDim.x + threadIdx.x;
    int stride = gridDim.x * blockDim.x;
    for (; i < n4; i += stride) {
        floatx4 v = reinterpret_cast<const floatx4*>(x)[i];
        u16x4 o;
        #pragma unroll
        for (int j = 0; j < 4; ++j) o[j] = f2b(v[j]);
        reinterpret_cast<u16x4*>(xb)[i] = o;
    }
}

// ---------------- cast + transpose 4 weights: T[n][k] = W[k][n] ----------------
__global__ void transpose_cast_w(const float* __restrict__ W0, const float* __restrict__ W1,
                                 const float* __restrict__ W2, const float* __restrict__ W3,
                                 u16* __restrict__ T0, u16* __restrict__ T1,
                                 u16* __restrict__ T2, u16* __restrict__ T3) {
    __shared__ float tile[32][33];
    const float* W; u16* T;
    switch (blockIdx.z) {
        case 0: W = W0; T = T0; break;
        case 1: W = W1; T = T1; break;
        case 2: W = W2; T = T2; break;
        default: W = W3; T = T3; break;
    }
    int bx = blockIdx.x * 32, by = blockIdx.y * 32;
    int tx = threadIdx.x, ty = threadIdx.y;
    #pragma unroll
    for (int i = 0; i < 4; ++i)
        tile[ty + i * 8][tx] = W[(size_t)(by + ty + i * 8) * Hdim + bx + tx];
    __syncthreads();
    #pragma unroll
    for (int i = 0; i < 4; ++i)
        T[(size_t)(bx + ty + i * 8) * Hdim + by + tx] = f2b(tile[tx][ty + i * 8]);
}

// ---------------- bf16 GEMM: C = A[M][K] * Bt[N][K]^T ---------------- (R6/R8 BK=32)
template <int MODE, int BN>
__global__ __launch_bounds__(256) void gemm_bt(const u16* __restrict__ A, const u16* __restrict__ Bt,
                                               void* __restrict__ C0, void* __restrict__ C1,
                                               void* __restrict__ C2, int N, int K) {
    constexpr int NB = BN / 32;  // col-frags per wave (wave covers BN/2 cols)
    __shared__ __align__(16) u16 As[128 * 32];
    __shared__ __align__(16) u16 Bs[BN * 32];
    const int tid = threadIdx.x;
    const int lane = tid & 63, wid = tid >> 6;
    const int wr = wid >> 1, wc = wid & 1;
    const int fr = lane & 15, g = lane >> 4, k8 = g * 8;
    const int rowBase = blockIdx.y * 128, colBase = blockIdx.x * BN;
    const int sr = lane >> 2, sc = (lane & 3) * 8;
    f32x4 acc[4][NB] = {};
    for (int k0 = 0; k0 < K; k0 += 32) {
        __syncthreads();
        #pragma unroll
        for (int i = 0; i < 2; ++i) {
            const int rb = wid * 32 + i * 16;
            gload16(&A[(size_t)(rowBase + rb + sr) * K + k0 + sc], &As[rb * 32]);
        }
        if constexpr (BN == 128) {
            #pragma unroll
            for (int i = 0; i < 2; ++i) {
                const int rb = wid * 32 + i * 16;
                gload16(&Bt[(size_t)(colBase + rb + sr) * K + k0 + sc], &Bs[rb * 32]);
            }
        } else {
            const int rb = wid * 16;
            gload16(&Bt[(size_t)(colBase + rb + sr) * K + k0 + sc], &Bs[rb * 32]);
        }
        __syncthreads();
        bf16x8 af[4], bfr[NB];
        #pragma unroll
        for (int m = 0; m < 4; ++m)
            af[m] = *reinterpret_cast<const bf16x8*>(&As[(wr * 64 + m * 16 + fr) * 32 + k8]);
        #pragma unroll
        for (int n = 0; n < NB; ++n)
            bfr[n] = *reinterpret_cast<const bf16x8*>(&Bs[(wc * (BN / 2) + n * 16 + fr) * 32 + k8]);
        #pragma unroll
        for (int m = 0; m < 4; ++m)
            #pragma unroll
            for (int n = 0; n < NB; ++n)
                acc[m][n] = __builtin_amdgcn_mfma_f32_16x16x32_bf16(af[m], bfr[n], acc[m][n], 0, 0, 0);
    }
    #pragma unroll
    for (int m = 0; m < 4; ++m) {
        #pragma unroll
        for (int n = 0; n < NB; ++n) {
            const int row = rowBase + wr * 64 + m * 16 + g * 4;
            const int col = colBase + wc * (BN / 2) + n * 16 + fr;
            if constexpr (MODE == 0) {
                u16* C = (u16*)C0;
                #pragma unroll
                for (int j = 0; j < 4; ++j) C[(size_t)(row + j) * N + col] = f2b(acc[m][n][j]);
            } else if constexpr (MODE == 1) {
                float* C = (float*)C0;
                #pragma unroll
                for (int j = 0; j < 4; ++j) C[(size_t)(row + j) * N + col] = acc[m][n][j];
            } else {
                if (col < 1024) {
                    u16* Qm = (u16*)C0;
                    #pragma unroll
                    for (int j = 0; j < 4; ++j) Qm[(size_t)(row + j) * 1024 + col] = f2b(acc[m][n][j]);
                } else if (col < 2048) {
                    u16* Km = (u16*)C1;
                    #pragma unroll
                    for (int j = 0; j < 4; ++j) Km[(size_t)(row + j) * 1024 + (col - 1024)] = f2b(acc[m][n][j]);
                } else {
                    u16* Vt = (u16*)C2;
                    u16x4 pk;
                    #pragma unroll
                    for (int j = 0; j < 4; ++j) pk[j] = f2b(acc[m][n][j]);
                    *reinterpret_cast<u16x4*>(&Vt[(size_t)(col - 2048) * NTOK + row]) = pk;
                }
            }
        }
    }
}

// ---------------- causal flash attention, pair-balanced, SWAPPED QK^T ---------
// 512 uniform blocks (structure = R6/R8). NEW: s = mfma(K,Q) so each lane owns
// one q-row (q = lane&15) with kv = g*4+j+n*16 in registers -> row softmax is
// in-lane (15 fmax) + 2 shuffles, scalar m/l state, P stored as one u16x4
// (8B) per n. o-rescale alpha crosses lanes via 4 shfl on non-skip tiles only.
__global__ __launch_bounds__(256, 2) void attn_kernel(const u16* __restrict__ Q, const u16* __restrict__ Km,
                                                      const u16* __restrict__ VtG, u16* __restrict__ AO) {
    __shared__ __align__(16) u16 Kt[2][64 * 64];
    __shared__ __align__(16) u16 Vt[2][64 * 64];
    __shared__ __align__(16) u16 Pw[4][16][72];
    const int tid = threadIdx.x, lane = tid & 63, w = tid >> 6;
    const int bid = blockIdx.x;
    const int xg = bid & 7, rem = bid >> 3;
    const int p = rem & 15, yg = rem >> 4;
    const int grp = xg + 8 * yg;          // (h,b) group 0..31
    const int h = grp & 15, b = grp >> 4;
    const int qsel[2] = { p, 31 - p };
    const int h0 = h * Dh;
    const size_t boff = (size_t)b * Sdim * Hdim;
    const u16* Qb = Q + boff;
    u16* AOb = AO + boff;
    const int fr = lane & 15, g = lane >> 4;

    // staging lane geometry (pre-swizzled source cols)
    const int lr = lane >> 3;
    const int lc8 = ((lane & 7) ^ lr) * 8;
    const u16* Kg = Km + boff + (size_t)(w * 8 + lr) * Hdim + h0 + lc8;
    const u16* Vg = VtG + (size_t)(h0 + w * 8 + lr) * NTOK + (size_t)b * Sdim + lc8;

    auto stage = [&](int t, int bufi) {
        const int kv0 = t * 64;
        #pragma unroll
        for (int i = 0; i < 2; ++i) {
            gload16(Kg + (size_t)(kv0 + i * 32) * Hdim, &Kt[bufi][w * 512 + i * 2048]);
            gload16(Vg + (size_t)(i * 32) * NTOK + kv0, &Vt[bufi][w * 512 + i * 2048]);
        }
    };

    // Q fragments for both q-blocks, prescaled by 1/8 * log2(e) (exp -> exp2)
    constexpr float QSCALE = 0.125f * 1.44269504089f;
    bf16x8 qf[2][2];
    int qrow0[2];
    #pragma unroll
    for (int m = 0; m < 2; ++m) {
        qrow0[m] = qsel[m] * 64 + w * 16;
        #pragma unroll
        for (int c = 0; c < 2; ++c) {
            bf16x8 t = *reinterpret_cast<const bf16x8*>(
                &Qb[(size_t)(qrow0[m] + fr) * Hdim + h0 + c * 32 + g * 8]);
            bf16x8 r;
            #pragma unroll
            for (int j = 0; j < 8; ++j) r[j] = (__bf16)((float)t[j] * QSCALE);
            qf[m][c] = r;
        }
    }

    // o[m][n][j]: q-row = g*4+j, d = n*16+fr. m/l state: per-lane scalar for
    // q-row (lane&15) of each q-block (softmax layout after swapped QK^T).
    f32x4 o[2][4] = {};
    float mrow[2] = { -INFINITY, -INFINITY };
    float lrow[2] = { 0.f, 0.f };

    const int ntiles = qsel[1] + 1;
    stage(0, 0);
    __syncthreads();
    int buf = 0;
    for (int t = 0; t < ntiles; ++t) {
        if (t + 1 < ntiles) stage(t + 1, buf ^ 1);
        const int kv0 = t * 64;
        #pragma unroll
        for (int m = 0; m < 2; ++m) {
            if (t > qsel[m]) continue;            // block-uniform
            const bool masked = (t == qsel[m]);
            // ---- QK^T (swapped): s[n] row=kv (g*4+j), col=q (fr) ----
            f32x4 s[4];
            __builtin_amdgcn_s_setprio(1);
            #pragma unroll
            for (int n = 0; n < 4; ++n) {
                const int row = n * 16 + fr;
                const int sw = (row & 7) << 3;
                const u16* kp = &Kt[buf][row * 64];
                bf16x8 kf0 = *reinterpret_cast<const bf16x8*>(&kp[(g * 8) ^ sw]);
                bf16x8 kf1 = *reinterpret_cast<const bf16x8*>(&kp[(32 + g * 8) ^ sw]);
                f32x4 z = {};
                z = __builtin_amdgcn_mfma_f32_16x16x32_bf16(kf0, qf[m][0], z, 0, 0, 0);
                s[n] = __builtin_amdgcn_mfma_f32_16x16x32_bf16(kf1, qf[m][1], z, 0, 0, 0);
            }
            __builtin_amdgcn_s_setprio(0);
            // ---- softmax: lane owns q-row (qrow0[m]+fr), kv = kv0+n*16+g*4+j
            if (masked) {
                const int qr = qrow0[m] + fr;
                #pragma unroll
                for (int n = 0; n < 4; ++n)
                    #pragma unroll
                    for (int j = 0; j < 4; ++j) {
                        const int kv = kv0 + n * 16 + g * 4 + j;
                        if (kv > qr) s[n][j] = -3.0e38f;
                    }
            }
            float mx = -3.0e38f;
            #pragma unroll
            for (int n = 0; n < 4; ++n)
                mx = fmaxf(mx, fmaxf(fmaxf(s[n][0], s[n][1]), fmaxf(s[n][2], s[n][3])));
            mx = fmaxf(mx, __shfl_xor(mx, 16));
            mx = fmaxf(mx, __shfl_xor(mx, 32));
            const bool skip = (__all(mx <= mrow[m] + 8.0f) != 0);   // wave-uniform
            const float mnew = skip ? mrow[m] : fmaxf(mrow[m], mx);
            float rs = 0.f;
            #pragma unroll
            for (int n = 0; n < 4; ++n) {
                u16x4 pk;
                #pragma unroll
                for (int j = 0; j < 4; ++j) {
                    const float pv = exp2f(s[n][j] - mnew);
                    rs += pv;
                    pk[j] = f2b(pv);
                }
                *reinterpret_cast<u16x4*>(&Pw[w][fr][n * 16 + g * 4]) = pk;
            }
            rs += __shfl_xor(rs, 16);
            rs += __shfl_xor(rs, 32);
            if (skip) {
                lrow[m] += rs;
            } else {
                const float alpha = exp2f(mrow[m] - mnew);
                lrow[m] = lrow[m] * alpha + rs;
                mrow[m] = mnew;
                #pragma unroll
                for (int j = 0; j < 4; ++j) {
                    const float aj = __shfl(alpha, g * 4 + j);
                    #pragma unroll
                    for (int n = 0; n < 4; ++n) o[m][n][j] *= aj;
                }
            }
            // ---- PV: pa row = fr (q), k = kv; same read layout as before ----
            bf16x8 pa0 = *reinterpret_cast<const bf16x8*>(&Pw[w][fr][g * 8]);
            bf16x8 pa1 = *reinterpret_cast<const bf16x8*>(&Pw[w][fr][32 + g * 8]);
            __builtin_amdgcn_s_setprio(1);
            #pragma unroll
            for (int n = 0; n < 4; ++n) {
                const int row = n * 16 + fr;
                const int sw = (row & 7) << 3;
                const u16* vp = &Vt[buf][row * 64];
                bf16x8 vf0 = *reinterpret_cast<const bf16x8*>(&vp[(g * 8) ^ sw]);
                bf16x8 vf1 = *reinterpret_cast<const bf16x8*>(&vp[(32 + g * 8) ^ sw]);
                o[m][n] = __builtin_amdgcn_mfma_f32_16x16x32_bf16(pa0, vf0, o[m][n], 0, 0, 0);
                o[m][n] = __builtin_amdgcn_mfma_f32_16x16x32_bf16(pa1, vf1, o[m][n], 0, 0, 0);
            }
            __builtin_amdgcn_s_setprio(0);
        }
        __syncthreads();
        buf ^= 1;
    }

    #pragma unroll
    for (int m = 0; m < 2; ++m) {
        const float invl = 1.0f / lrow[m];
        #pragma unroll
        for (int j = 0; j < 4; ++j) {
            const float ij = __shfl(invl, g * 4 + j);
            const int qrow = qrow0[m] + g * 4 + j;
            #pragma unroll
            for (int n = 0; n < 4; ++n)
                AOb[(size_t)qrow * Hdim + h0 + n * 16 + fr] = f2b(o[m][n][j] * ij);
        }
    }
}

extern "C" void kernel_launch(void* const* d_in, const int* in_sizes, int n_in,
                              void* d_out, int out_size, void* d_ws, size_t ws_size,
                              hipStream_t stream) {
    const float* x  = (const float*)d_in[0];
    // d_in[1] = causal mask — applied analytically
    const float* Wq = (const float*)d_in[2];
    const float* Wk = (const float*)d_in[3];
    const float* Wv = (const float*)d_in[4];
    const float* Wo = (const float*)d_in[5];
    float* out = (float*)d_out;

    u16* ws  = (u16*)d_ws;
    u16* Xb  = ws;                    // 4096x1024
    u16* WqT = ws  + 4194304;         // 3x 1024x1024 contiguous => fused QKV B
    u16* WkT = WqT + 1048576;
    u16* WvT = WkT + 1048576;
    u16* WoT = WvT + 1048576;
    u16* Qm  = WoT + 1048576;         // 4096x1024 token-major
    u16* Km  = Qm  + 4194304;
    u16* Vt  = Km  + 4194304;         // V^T: [1024 hd][4096 token]
    u16* AO  = Vt  + 4194304;

    cast_x_kernel<<<2048, 256, 0, stream>>>(x, Xb, NTOK * Hdim / 4);
    transpose_cast_w<<<dim3(32, 32, 4), dim3(32, 8), 0, stream>>>(Wq, Wk, Wv, Wo, WqT, WkT, WvT, WoT);
    gemm_bt<2, 128><<<dim3(24, 32), 256, 0, stream>>>(Xb, WqT, Qm, Km, Vt, 3072, Hdim);
    attn_kernel<<<dim3(512), 256, 0, stream>>>(Qm, Km, Vt, AO);
    gemm_bt<1, 64><<<dim3(16, 32), 256, 0, stream>>>(AO, WoT, out, nullptr, nullptr, Hdim, Hdim);
}